// Round 9
// baseline (1668.480 us; speedup 1.0000x reference)
//
#include <hip/hip_runtime.h>

// MinkowskiConcat forward, slot-direct (R9 = R8 + gather occupancy probe):
//   place: pos = atomicAdd(cnt[key]); pos<4 -> slots[4*key+pos]=in_row; else overflow.
//   gather: per output row, int4 cnt load + int4 slot loads (NT) -> <=4 feat rows ->
//   NT full-row store. __launch_bounds__(256,8) pins 8 waves/SIMD (H2 probe).
//   fixup: rare overflow entries via f32 atomics.
//   Fallbacks: CSR path then atomic path (ws-size dependent).

constexpr int C_IN  = 128;
constexpr int C_OUT = 256;
constexpr int RPW   = 4;
constexpr int NSLOT = 4;
constexpr int OVF_CAP = 262144;
constexpr int SCAN_TPB = 256;
constexpr int SCAN_EPT = 16;
constexpr int SCAN_EPB = SCAN_TPB * SCAN_EPT;

typedef float f32x4 __attribute__((ext_vector_type(4)));
typedef int   i32x4 __attribute__((ext_vector_type(4)));

// ---------------- slot-direct path ----------------

__global__ __launch_bounds__(256)
void place_slots_kernel(const int* __restrict__ m1i, const int* __restrict__ m1o,
                        const int* __restrict__ m2i, const int* __restrict__ m2o,
                        int* __restrict__ cnt, int* __restrict__ slots,
                        int2* __restrict__ ovf, int* __restrict__ ovf_n,
                        int n1, int n2, int n_out) {
    int i = blockIdx.x * blockDim.x + threadIdx.x;
    int n = n1 + n2;
    if (i >= n) return;
    int key, in_row;
    if (i < n1) { key = m1o[i];              in_row = m1i[i]; }
    else        { key = n_out + m2o[i - n1]; in_row = m2i[i - n1]; }
    int pos = atomicAdd(&cnt[key], 1);
    if (pos < NSLOT) {
        slots[(long)key * NSLOT + pos] = in_row;
    } else {
        int p = atomicAdd(ovf_n, 1);
        if (p < OVF_CAP) ovf[p] = make_int2(key, in_row);
    }
}

// unguarded: requires n_out % RPW == 0 (holds: 786432 % 4 == 0)
__global__ __launch_bounds__(256, 8)
void gather_slots_kernel(const float* __restrict__ feat1,
                         const float* __restrict__ feat2,
                         const int* __restrict__ cnt,
                         const int* __restrict__ slots,
                         float* __restrict__ out, int n_out) {
    int wid  = (blockIdx.x * blockDim.x + threadIdx.x) >> 6;
    int lane = threadIdx.x & 63;
    int side = lane >> 5;
    int l    = lane & 31;
    long r0  = (long)wid * RPW;

    const float* feat = side ? feat2 : feat1;
    const long kbase  = (side ? (long)n_out : 0) + r0;

    // one int4 cnt load per half-wave (kbase % 4 == 0), NT: single-use stream
    i32x4 c4 = __builtin_nontemporal_load(
        reinterpret_cast<const i32x4*>(cnt + kbase));

    // slot int4 loads, NT
    i32x4 s[RPW];
    #pragma unroll
    for (int k = 0; k < RPW; ++k)
        s[k] = __builtin_nontemporal_load(
            reinterpret_cast<const i32x4*>(slots + (kbase + k) * NSLOT));

    f32x4 acc[RPW];
    #pragma unroll
    for (int k = 0; k < RPW; ++k) {
        f32x4 v = {0.f, 0.f, 0.f, 0.f};
        if (c4[k] > 0)
            v = *reinterpret_cast<const f32x4*>(feat + (long)s[k].x * C_IN + l * 4);
        acc[k] = v;
    }
    #pragma unroll
    for (int k = 0; k < RPW; ++k)
        if (c4[k] > 1)
            acc[k] += *reinterpret_cast<const f32x4*>(feat + (long)s[k].y * C_IN + l * 4);
    #pragma unroll
    for (int k = 0; k < RPW; ++k)
        if (c4[k] > 2)
            acc[k] += *reinterpret_cast<const f32x4*>(feat + (long)s[k].z * C_IN + l * 4);
    #pragma unroll
    for (int k = 0; k < RPW; ++k)
        if (c4[k] > 3)
            acc[k] += *reinterpret_cast<const f32x4*>(feat + (long)s[k].w * C_IN + l * 4);

    #pragma unroll
    for (int k = 0; k < RPW; ++k) {
        f32x4* dst = reinterpret_cast<f32x4*>(out + (r0 + k) * C_OUT + side * C_IN + l * 4);
        __builtin_nontemporal_store(acc[k], dst);
    }
}

__global__ __launch_bounds__(256)
void fixup_kernel(const float* __restrict__ feat1, const float* __restrict__ feat2,
                  const int2* __restrict__ ovf, const int* __restrict__ ovf_n,
                  float* __restrict__ out, int n_out) {
    int wid  = (blockIdx.x * blockDim.x + threadIdx.x) >> 6;
    int lane = threadIdx.x & 63;
    int total = *ovf_n;
    if (total > OVF_CAP) total = OVF_CAP;
    int nw = (gridDim.x * blockDim.x) >> 6;
    for (int e = wid; e < total; e += nw) {
        int2 kr  = ovf[e];
        int side = (kr.x >= n_out) ? 1 : 0;
        long r   = kr.x - (side ? n_out : 0);
        const float* feat = side ? feat2 : feat1;
        const float2 v = *reinterpret_cast<const float2*>(feat + (long)kr.y * C_IN + lane * 2);
        float* dst = out + r * C_OUT + side * C_IN + lane * 2;
        unsafeAtomicAdd(dst,     v.x);
        unsafeAtomicAdd(dst + 1, v.y);
    }
}

// ---------------- CSR fallback path ----------------

__global__ void count_kernel(const int* __restrict__ m1o, const int* __restrict__ m2o,
                             int* __restrict__ counts, int n1, int n2, int n_out) {
    int i = blockIdx.x * blockDim.x + threadIdx.x;
    int n = n1 + n2;
    if (i >= n) return;
    if (i < n1) atomicAdd(&counts[m1o[i]], 1);
    else        atomicAdd(&counts[n_out + m2o[i - n1]], 1);
}

__global__ void scan_blocksums_kernel(const int* __restrict__ counts, int nc,
                                      int* __restrict__ blksums) {
    __shared__ int sdata[SCAN_TPB];
    int base = blockIdx.x * SCAN_EPB + threadIdx.x * SCAN_EPT;
    int s = 0;
    #pragma unroll
    for (int k = 0; k < SCAN_EPT; ++k) {
        int idx = base + k;
        s += (idx < nc) ? counts[idx] : 0;
    }
    sdata[threadIdx.x] = s;
    __syncthreads();
    for (int off = SCAN_TPB / 2; off > 0; off >>= 1) {
        if (threadIdx.x < off) sdata[threadIdx.x] += sdata[threadIdx.x + off];
        __syncthreads();
    }
    if (threadIdx.x == 0) blksums[blockIdx.x] = sdata[0];
}

__global__ void scan_top_kernel(int* __restrict__ blksums, int nblk,
                                int* __restrict__ offsets, int nc) {
    __shared__ int sdata[512];
    int t = threadIdx.x;
    int v = (t < nblk) ? blksums[t] : 0;
    sdata[t] = v;
    __syncthreads();
    for (int off = 1; off < 512; off <<= 1) {
        int x = (t >= off) ? sdata[t - off] : 0;
        __syncthreads();
        sdata[t] += x;
        __syncthreads();
    }
    if (t < nblk) blksums[t] = sdata[t] - v;
    if (t == 511) offsets[nc] = sdata[511];
}

__global__ void scan_write_kernel(const int* __restrict__ counts, int nc,
                                  const int* __restrict__ blksums,
                                  int* __restrict__ offsets, int* __restrict__ cursor) {
    __shared__ int sdata[SCAN_TPB];
    int t = threadIdx.x;
    int base = blockIdx.x * SCAN_EPB + t * SCAN_EPT;
    int local[SCAN_EPT];
    int s = 0;
    #pragma unroll
    for (int k = 0; k < SCAN_EPT; ++k) {
        int idx = base + k;
        int c = (idx < nc) ? counts[idx] : 0;
        local[k] = s;
        s += c;
    }
    sdata[t] = s;
    __syncthreads();
    for (int off = 1; off < SCAN_TPB; off <<= 1) {
        int x = (t >= off) ? sdata[t - off] : 0;
        __syncthreads();
        sdata[t] += x;
        __syncthreads();
    }
    int thread_excl = sdata[t] - s;
    int prefix = blksums[blockIdx.x] + thread_excl;
    #pragma unroll
    for (int k = 0; k < SCAN_EPT; ++k) {
        int idx = base + k;
        if (idx < nc) {
            int o = prefix + local[k];
            offsets[idx] = o;
            cursor[idx]  = o;
        }
    }
}

__global__ void place_kernel(const int* __restrict__ m1i, const int* __restrict__ m1o,
                             const int* __restrict__ m2i, const int* __restrict__ m2o,
                             int* __restrict__ cursor, int* __restrict__ idxpool,
                             int n1, int n2, int n_out) {
    int i = blockIdx.x * blockDim.x + threadIdx.x;
    int n = n1 + n2;
    if (i >= n) return;
    if (i < n1) {
        int pos = atomicAdd(&cursor[m1o[i]], 1);
        idxpool[pos] = m1i[i];
    } else {
        int j = i - n1;
        int pos = atomicAdd(&cursor[n_out + m2o[j]], 1);
        idxpool[pos] = m2i[j];
    }
}

template <bool GUARDED>
__global__ __launch_bounds__(256)
void gather_csr_kernel(const float* __restrict__ feat1,
                       const float* __restrict__ feat2,
                       const int* __restrict__ offsets,
                       const int* __restrict__ idxpool,
                       float* __restrict__ out, int n_out) {
    int wid  = (blockIdx.x * blockDim.x + threadIdx.x) >> 6;
    int lane = threadIdx.x & 63;
    int side = lane >> 5;
    int l    = lane & 31;
    long r0  = (long)wid * RPW;
    if (GUARDED && r0 >= n_out) return;

    const float* feat = side ? feat2 : feat1;
    const long obase  = side ? n_out : 0;

    int off[RPW + 1];
    #pragma unroll
    for (int k = 0; k <= RPW; ++k) {
        long r = r0 + k;
        if (GUARDED && r > n_out) r = n_out;
        off[k] = offsets[obase + r];
    }

    int i0[RPW], i1[RPW];
    #pragma unroll
    for (int k = 0; k < RPW; ++k) {
        int b = off[k], e = off[k + 1];
        i0[k] = (b < e)     ? idxpool[b]     : -1;
        i1[k] = (b + 1 < e) ? idxpool[b + 1] : -1;
    }

    f32x4 acc[RPW];
    #pragma unroll
    for (int k = 0; k < RPW; ++k) {
        f32x4 v = {0.f, 0.f, 0.f, 0.f};
        if (i0[k] >= 0)
            v = *reinterpret_cast<const f32x4*>(feat + (long)i0[k] * C_IN + l * 4);
        acc[k] = v;
    }
    #pragma unroll
    for (int k = 0; k < RPW; ++k)
        if (i1[k] >= 0)
            acc[k] += *reinterpret_cast<const f32x4*>(feat + (long)i1[k] * C_IN + l * 4);
    #pragma unroll
    for (int k = 0; k < RPW; ++k)
        for (int p = off[k] + 2; p < off[k + 1]; ++p) {
            int ir = idxpool[p];
            acc[k] += *reinterpret_cast<const f32x4*>(feat + (long)ir * C_IN + l * 4);
        }
    #pragma unroll
    for (int k = 0; k < RPW; ++k) {
        long r = r0 + k;
        if (!GUARDED || r < n_out) {
            f32x4* dst = reinterpret_cast<f32x4*>(out + r * C_OUT + side * C_IN + l * 4);
            __builtin_nontemporal_store(acc[k], dst);
        }
    }
}

// ---------------- atomic last-resort path ----------------

__global__ void zero_out_kernel(float4* __restrict__ out, long n4) {
    long i = (long)blockIdx.x * blockDim.x + threadIdx.x;
    long stride = (long)gridDim.x * blockDim.x;
    const float4 z = {0.f, 0.f, 0.f, 0.f};
    for (; i < n4; i += stride) out[i] = z;
}

__global__ void scatter_add_kernel(const float* __restrict__ feat,
                                   const int* __restrict__ map_in,
                                   const int* __restrict__ map_out,
                                   float* __restrict__ out,
                                   int n_rows, int col_off) {
    int gid = blockIdx.x * blockDim.x + threadIdx.x;
    int row = gid >> 6;
    int t   = gid & 63;
    if (row >= n_rows) return;
    int in_row  = map_in[row];
    int out_row = map_out[row];
    const float2 v = *reinterpret_cast<const float2*>(feat + (long)in_row * C_IN + t * 2);
    float* dst = out + (long)out_row * C_OUT + col_off + t * 2;
    unsafeAtomicAdd(dst,     v.x);
    unsafeAtomicAdd(dst + 1, v.y);
}

extern "C" void kernel_launch(void* const* d_in, const int* in_sizes, int n_in,
                              void* d_out, int out_size, void* d_ws, size_t ws_size,
                              hipStream_t stream) {
    const float* feat1    = (const float*)d_in[0];
    const float* feat2    = (const float*)d_in[1];
    const int*   map1_in  = (const int*)d_in[2];
    const int*   map1_out = (const int*)d_in[3];
    const int*   map2_in  = (const int*)d_in[4];
    const int*   map2_out = (const int*)d_in[5];
    float*       out      = (float*)d_out;

    const int n1    = in_sizes[0] / C_IN;      // 524288
    const int n2    = in_sizes[1] / C_IN;      // 524288
    const int n_out = out_size / C_OUT;        // 786432
    const int nc    = 2 * n_out;
    const int n     = n1 + n2;

    size_t need_slots = ((size_t)nc * (1 + NSLOT) + 2 * (size_t)OVF_CAP + 16) * sizeof(int);
    size_t need_csr   = ((size_t)3 * nc + 1 + 512 + n1 + n2) * sizeof(int);
    const int nblk    = (nc + SCAN_EPB - 1) / SCAN_EPB;

    if (ws_size >= need_slots && (n_out % RPW) == 0) {
        int*  cnt   = (int*)d_ws;
        int*  slots = cnt + nc;
        int2* ovf   = (int2*)(slots + (size_t)NSLOT * nc);
        int*  ovf_n = (int*)(ovf + OVF_CAP);

        (void)hipMemsetAsync(cnt, 0, (size_t)nc * sizeof(int), stream);
        (void)hipMemsetAsync(ovf_n, 0, sizeof(int), stream);

        place_slots_kernel<<<(n + 255) / 256, 256, 0, stream>>>(
            map1_in, map1_out, map2_in, map2_out, cnt, slots, ovf, ovf_n, n1, n2, n_out);

        long waves   = (long)n_out / RPW;
        long threads = waves * 64;
        gather_slots_kernel<<<(int)(threads / 256), 256, 0, stream>>>(
            feat1, feat2, cnt, slots, out, n_out);

        fixup_kernel<<<512, 256, 0, stream>>>(feat1, feat2, ovf, ovf_n, out, n_out);
    } else if (ws_size >= need_csr && nblk <= 512) {
        int* counts  = (int*)d_ws;
        int* offsets = counts + nc;
        int* cursor  = offsets + nc + 1;
        int* blksums = cursor + nc;
        int* idxpool = blksums + 512;

        (void)hipMemsetAsync(counts, 0, (size_t)nc * sizeof(int), stream);
        count_kernel<<<(n + 255) / 256, 256, 0, stream>>>(
            map1_out, map2_out, counts, n1, n2, n_out);
        scan_blocksums_kernel<<<nblk, SCAN_TPB, 0, stream>>>(counts, nc, blksums);
        scan_top_kernel<<<1, 512, 0, stream>>>(blksums, nblk, offsets, nc);
        scan_write_kernel<<<nblk, SCAN_TPB, 0, stream>>>(counts, nc, blksums, offsets, cursor);
        place_kernel<<<(n + 255) / 256, 256, 0, stream>>>(
            map1_in, map1_out, map2_in, map2_out, cursor, idxpool, n1, n2, n_out);

        long waves   = ((long)n_out + RPW - 1) / RPW;
        long threads = waves * 64;
        int  blocks  = (int)((threads + 255) / 256);
        if (n_out % RPW == 0)
            gather_csr_kernel<false><<<blocks, 256, 0, stream>>>(
                feat1, feat2, offsets, idxpool, out, n_out);
        else
            gather_csr_kernel<true><<<blocks, 256, 0, stream>>>(
                feat1, feat2, offsets, idxpool, out, n_out);
    } else {
        long n4 = (long)out_size / 4;
        zero_out_kernel<<<2048, 256, 0, stream>>>((float4*)out, n4);
        scatter_add_kernel<<<(n1 + 3) / 4, 256, 0, stream>>>(
            feat1, map1_in, map1_out, out, n1, 0);
        scatter_add_kernel<<<(n2 + 3) / 4, 256, 0, stream>>>(
            feat2, map2_in, map2_out, out, n2, C_IN);
    }
}

// Round 10
// 395.152 us; speedup vs baseline: 4.2224x; 4.2224x over previous
//
#include <hip/hip_runtime.h>

// MinkowskiConcat forward, slot-direct, side-split gather (R10):
//   place: pos = atomicAdd(cnt[key]); pos<4 -> slots[4*key+pos]=in_row; else overflow.
//   gather: TWO passes (one per side). Each pass reads ONE feat table ->
//   distinct working set 169MB < 256MB L3 -> repeat reads (37%) hit L3.
//   Wave handles 8 rows (4 per half-wave), int4 NT metadata loads,
//   NT 512B/row stores. __launch_bounds__(256) — R8's proven no-spill config
//   (R6/R9 lesson: tight VGPR caps => scratch spill => WRITE_SIZE x7).
//   fixup: rare overflow entries via f32 atomics.

constexpr int C_IN  = 128;
constexpr int C_OUT = 256;
constexpr int RPH   = 4;            // rows per half-wave
constexpr int RPW   = 2 * RPH;      // rows per wave (one side)
constexpr int NSLOT = 4;
constexpr int OVF_CAP = 262144;
constexpr int SCAN_TPB = 256;
constexpr int SCAN_EPT = 16;
constexpr int SCAN_EPB = SCAN_TPB * SCAN_EPT;

typedef float f32x4 __attribute__((ext_vector_type(4)));
typedef int   i32x4 __attribute__((ext_vector_type(4)));

// ---------------- slot-direct path ----------------

__global__ __launch_bounds__(256)
void place_slots_kernel(const int* __restrict__ m1i, const int* __restrict__ m1o,
                        const int* __restrict__ m2i, const int* __restrict__ m2o,
                        int* __restrict__ cnt, int* __restrict__ slots,
                        int2* __restrict__ ovf, int* __restrict__ ovf_n,
                        int n1, int n2, int n_out) {
    int i = blockIdx.x * blockDim.x + threadIdx.x;
    int n = n1 + n2;
    if (i >= n) return;
    int key, in_row;
    if (i < n1) { key = m1o[i];              in_row = m1i[i]; }
    else        { key = n_out + m2o[i - n1]; in_row = m2i[i - n1]; }
    int pos = atomicAdd(&cnt[key], 1);
    if (pos < NSLOT) {
        slots[(long)key * NSLOT + pos] = in_row;
    } else {
        int p = atomicAdd(ovf_n, 1);
        if (p < OVF_CAP) ovf[p] = make_int2(key, in_row);
    }
}

// One gather pass for ONE side. cnt/slots/out pre-offset by caller.
// Wave: 8 rows; half-wave h handles rows r0+4h .. r0+4h+3, 16B/lane.
// Requires n_out % RPW == 0 (786432 % 8 == 0).
__global__ __launch_bounds__(256)
void gather_side_kernel(const float* __restrict__ feat,
                        const int* __restrict__ cnt,
                        const int* __restrict__ slots,
                        float* __restrict__ out_side,   // out + side*C_IN
                        int n_out) {
    int wid  = (blockIdx.x * blockDim.x + threadIdx.x) >> 6;
    int lane = threadIdx.x & 63;
    int h    = lane >> 5;
    int l    = lane & 31;
    long r0  = (long)wid * RPW + (long)h * RPH;

    // int4 NT metadata loads (single-use streams; keep L3 for feat)
    i32x4 c4 = __builtin_nontemporal_load(
        reinterpret_cast<const i32x4*>(cnt + r0));

    i32x4 s[RPH];
    #pragma unroll
    for (int k = 0; k < RPH; ++k)
        s[k] = __builtin_nontemporal_load(
            reinterpret_cast<const i32x4*>(slots + (r0 + k) * NSLOT));

    f32x4 acc[RPH];
    #pragma unroll
    for (int k = 0; k < RPH; ++k) {
        f32x4 v = {0.f, 0.f, 0.f, 0.f};
        if (c4[k] > 0)
            v = *reinterpret_cast<const f32x4*>(feat + (long)s[k].x * C_IN + l * 4);
        acc[k] = v;
    }
    #pragma unroll
    for (int k = 0; k < RPH; ++k)
        if (c4[k] > 1)
            acc[k] += *reinterpret_cast<const f32x4*>(feat + (long)s[k].y * C_IN + l * 4);
    #pragma unroll
    for (int k = 0; k < RPH; ++k)
        if (c4[k] > 2)
            acc[k] += *reinterpret_cast<const f32x4*>(feat + (long)s[k].z * C_IN + l * 4);
    #pragma unroll
    for (int k = 0; k < RPH; ++k)
        if (c4[k] > 3)
            acc[k] += *reinterpret_cast<const f32x4*>(feat + (long)s[k].w * C_IN + l * 4);

    #pragma unroll
    for (int k = 0; k < RPH; ++k) {
        f32x4* dst = reinterpret_cast<f32x4*>(out_side + (r0 + k) * C_OUT + l * 4);
        __builtin_nontemporal_store(acc[k], dst);
    }
}

__global__ __launch_bounds__(256)
void fixup_kernel(const float* __restrict__ feat1, const float* __restrict__ feat2,
                  const int2* __restrict__ ovf, const int* __restrict__ ovf_n,
                  float* __restrict__ out, int n_out) {
    int wid  = (blockIdx.x * blockDim.x + threadIdx.x) >> 6;
    int lane = threadIdx.x & 63;
    int total = *ovf_n;
    if (total > OVF_CAP) total = OVF_CAP;
    int nw = (gridDim.x * blockDim.x) >> 6;
    for (int e = wid; e < total; e += nw) {
        int2 kr  = ovf[e];
        int side = (kr.x >= n_out) ? 1 : 0;
        long r   = kr.x - (side ? n_out : 0);
        const float* feat = side ? feat2 : feat1;
        const float2 v = *reinterpret_cast<const float2*>(feat + (long)kr.y * C_IN + lane * 2);
        float* dst = out + r * C_OUT + side * C_IN + lane * 2;
        unsafeAtomicAdd(dst,     v.x);
        unsafeAtomicAdd(dst + 1, v.y);
    }
}

// ---------------- CSR fallback path ----------------

__global__ void count_kernel(const int* __restrict__ m1o, const int* __restrict__ m2o,
                             int* __restrict__ counts, int n1, int n2, int n_out) {
    int i = blockIdx.x * blockDim.x + threadIdx.x;
    int n = n1 + n2;
    if (i >= n) return;
    if (i < n1) atomicAdd(&counts[m1o[i]], 1);
    else        atomicAdd(&counts[n_out + m2o[i - n1]], 1);
}

__global__ void scan_blocksums_kernel(const int* __restrict__ counts, int nc,
                                      int* __restrict__ blksums) {
    __shared__ int sdata[SCAN_TPB];
    int base = blockIdx.x * SCAN_EPB + threadIdx.x * SCAN_EPT;
    int s = 0;
    #pragma unroll
    for (int k = 0; k < SCAN_EPT; ++k) {
        int idx = base + k;
        s += (idx < nc) ? counts[idx] : 0;
    }
    sdata[threadIdx.x] = s;
    __syncthreads();
    for (int off = SCAN_TPB / 2; off > 0; off >>= 1) {
        if (threadIdx.x < off) sdata[threadIdx.x] += sdata[threadIdx.x + off];
        __syncthreads();
    }
    if (threadIdx.x == 0) blksums[blockIdx.x] = sdata[0];
}

__global__ void scan_top_kernel(int* __restrict__ blksums, int nblk,
                                int* __restrict__ offsets, int nc) {
    __shared__ int sdata[512];
    int t = threadIdx.x;
    int v = (t < nblk) ? blksums[t] : 0;
    sdata[t] = v;
    __syncthreads();
    for (int off = 1; off < 512; off <<= 1) {
        int x = (t >= off) ? sdata[t - off] : 0;
        __syncthreads();
        sdata[t] += x;
        __syncthreads();
    }
    if (t < nblk) blksums[t] = sdata[t] - v;
    if (t == 511) offsets[nc] = sdata[511];
}

__global__ void scan_write_kernel(const int* __restrict__ counts, int nc,
                                  const int* __restrict__ blksums,
                                  int* __restrict__ offsets, int* __restrict__ cursor) {
    __shared__ int sdata[SCAN_TPB];
    int t = threadIdx.x;
    int base = blockIdx.x * SCAN_EPB + t * SCAN_EPT;
    int local[SCAN_EPT];
    int s = 0;
    #pragma unroll
    for (int k = 0; k < SCAN_EPT; ++k) {
        int idx = base + k;
        int c = (idx < nc) ? counts[idx] : 0;
        local[k] = s;
        s += c;
    }
    sdata[t] = s;
    __syncthreads();
    for (int off = 1; off < SCAN_TPB; off <<= 1) {
        int x = (t >= off) ? sdata[t - off] : 0;
        __syncthreads();
        sdata[t] += x;
        __syncthreads();
    }
    int thread_excl = sdata[t] - s;
    int prefix = blksums[blockIdx.x] + thread_excl;
    #pragma unroll
    for (int k = 0; k < SCAN_EPT; ++k) {
        int idx = base + k;
        if (idx < nc) {
            int o = prefix + local[k];
            offsets[idx] = o;
            cursor[idx]  = o;
        }
    }
}

__global__ void place_kernel(const int* __restrict__ m1i, const int* __restrict__ m1o,
                             const int* __restrict__ m2i, const int* __restrict__ m2o,
                             int* __restrict__ cursor, int* __restrict__ idxpool,
                             int n1, int n2, int n_out) {
    int i = blockIdx.x * blockDim.x + threadIdx.x;
    int n = n1 + n2;
    if (i >= n) return;
    if (i < n1) {
        int pos = atomicAdd(&cursor[m1o[i]], 1);
        idxpool[pos] = m1i[i];
    } else {
        int j = i - n1;
        int pos = atomicAdd(&cursor[n_out + m2o[j]], 1);
        idxpool[pos] = m2i[j];
    }
}

template <bool GUARDED>
__global__ __launch_bounds__(256)
void gather_csr_kernel(const float* __restrict__ feat1,
                       const float* __restrict__ feat2,
                       const int* __restrict__ offsets,
                       const int* __restrict__ idxpool,
                       float* __restrict__ out, int n_out) {
    int wid  = (blockIdx.x * blockDim.x + threadIdx.x) >> 6;
    int lane = threadIdx.x & 63;
    int side = lane >> 5;
    int l    = lane & 31;
    long r0  = (long)wid * RPH;
    if (GUARDED && r0 >= n_out) return;

    const float* feat = side ? feat2 : feat1;
    const long obase  = side ? n_out : 0;

    int off[RPH + 1];
    #pragma unroll
    for (int k = 0; k <= RPH; ++k) {
        long r = r0 + k;
        if (GUARDED && r > n_out) r = n_out;
        off[k] = offsets[obase + r];
    }

    int i0[RPH], i1[RPH];
    #pragma unroll
    for (int k = 0; k < RPH; ++k) {
        int b = off[k], e = off[k + 1];
        i0[k] = (b < e)     ? idxpool[b]     : -1;
        i1[k] = (b + 1 < e) ? idxpool[b + 1] : -1;
    }

    f32x4 acc[RPH];
    #pragma unroll
    for (int k = 0; k < RPH; ++k) {
        f32x4 v = {0.f, 0.f, 0.f, 0.f};
        if (i0[k] >= 0)
            v = *reinterpret_cast<const f32x4*>(feat + (long)i0[k] * C_IN + l * 4);
        acc[k] = v;
    }
    #pragma unroll
    for (int k = 0; k < RPH; ++k)
        if (i1[k] >= 0)
            acc[k] += *reinterpret_cast<const f32x4*>(feat + (long)i1[k] * C_IN + l * 4);
    #pragma unroll
    for (int k = 0; k < RPH; ++k)
        for (int p = off[k] + 2; p < off[k + 1]; ++p) {
            int ir = idxpool[p];
            acc[k] += *reinterpret_cast<const f32x4*>(feat + (long)ir * C_IN + l * 4);
        }
    #pragma unroll
    for (int k = 0; k < RPH; ++k) {
        long r = r0 + k;
        if (!GUARDED || r < n_out) {
            f32x4* dst = reinterpret_cast<f32x4*>(out + r * C_OUT + side * C_IN + l * 4);
            __builtin_nontemporal_store(acc[k], dst);
        }
    }
}

// ---------------- atomic last-resort path ----------------

__global__ void zero_out_kernel(float4* __restrict__ out, long n4) {
    long i = (long)blockIdx.x * blockDim.x + threadIdx.x;
    long stride = (long)gridDim.x * blockDim.x;
    const float4 z = {0.f, 0.f, 0.f, 0.f};
    for (; i < n4; i += stride) out[i] = z;
}

__global__ void scatter_add_kernel(const float* __restrict__ feat,
                                   const int* __restrict__ map_in,
                                   const int* __restrict__ map_out,
                                   float* __restrict__ out,
                                   int n_rows, int col_off) {
    int gid = blockIdx.x * blockDim.x + threadIdx.x;
    int row = gid >> 6;
    int t   = gid & 63;
    if (row >= n_rows) return;
    int in_row  = map_in[row];
    int out_row = map_out[row];
    const float2 v = *reinterpret_cast<const float2*>(feat + (long)in_row * C_IN + t * 2);
    float* dst = out + (long)out_row * C_OUT + col_off + t * 2;
    unsafeAtomicAdd(dst,     v.x);
    unsafeAtomicAdd(dst + 1, v.y);
}

extern "C" void kernel_launch(void* const* d_in, const int* in_sizes, int n_in,
                              void* d_out, int out_size, void* d_ws, size_t ws_size,
                              hipStream_t stream) {
    const float* feat1    = (const float*)d_in[0];
    const float* feat2    = (const float*)d_in[1];
    const int*   map1_in  = (const int*)d_in[2];
    const int*   map1_out = (const int*)d_in[3];
    const int*   map2_in  = (const int*)d_in[4];
    const int*   map2_out = (const int*)d_in[5];
    float*       out      = (float*)d_out;

    const int n1    = in_sizes[0] / C_IN;      // 524288
    const int n2    = in_sizes[1] / C_IN;      // 524288
    const int n_out = out_size / C_OUT;        // 786432
    const int nc    = 2 * n_out;
    const int n     = n1 + n2;

    size_t need_slots = ((size_t)nc * (1 + NSLOT) + 2 * (size_t)OVF_CAP + 16) * sizeof(int);
    size_t need_csr   = ((size_t)3 * nc + 1 + 512 + n1 + n2) * sizeof(int);
    const int nblk    = (nc + SCAN_EPB - 1) / SCAN_EPB;

    if (ws_size >= need_slots && (n_out % RPW) == 0) {
        int*  cnt   = (int*)d_ws;
        int*  slots = cnt + nc;
        int2* ovf   = (int2*)(slots + (size_t)NSLOT * nc);
        int*  ovf_n = (int*)(ovf + OVF_CAP);

        (void)hipMemsetAsync(cnt, 0, (size_t)nc * sizeof(int), stream);
        (void)hipMemsetAsync(ovf_n, 0, sizeof(int), stream);

        place_slots_kernel<<<(n + 255) / 256, 256, 0, stream>>>(
            map1_in, map1_out, map2_in, map2_out, cnt, slots, ovf, ovf_n, n1, n2, n_out);

        int blocks = (int)(((long)n_out / RPW * 64) / 256);
        // pass A: side 1 (reads only feat1 -> 169MB distinct, L3-resident)
        gather_side_kernel<<<blocks, 256, 0, stream>>>(
            feat1, cnt, slots, out, n_out);
        // pass B: side 2
        gather_side_kernel<<<blocks, 256, 0, stream>>>(
            feat2, cnt + n_out, slots + (size_t)n_out * NSLOT, out + C_IN, n_out);

        fixup_kernel<<<512, 256, 0, stream>>>(feat1, feat2, ovf, ovf_n, out, n_out);
    } else if (ws_size >= need_csr && nblk <= 512) {
        int* counts  = (int*)d_ws;
        int* offsets = counts + nc;
        int* cursor  = offsets + nc + 1;
        int* blksums = cursor + nc;
        int* idxpool = blksums + 512;

        (void)hipMemsetAsync(counts, 0, (size_t)nc * sizeof(int), stream);
        count_kernel<<<(n + 255) / 256, 256, 0, stream>>>(
            map1_out, map2_out, counts, n1, n2, n_out);
        scan_blocksums_kernel<<<nblk, SCAN_TPB, 0, stream>>>(counts, nc, blksums);
        scan_top_kernel<<<1, 512, 0, stream>>>(blksums, nblk, offsets, nc);
        scan_write_kernel<<<nblk, SCAN_TPB, 0, stream>>>(counts, nc, blksums, offsets, cursor);
        place_kernel<<<(n + 255) / 256, 256, 0, stream>>>(
            map1_in, map1_out, map2_in, map2_out, cursor, idxpool, n1, n2, n_out);

        long waves   = ((long)n_out + RPH - 1) / RPH;
        long threads = waves * 64;
        int  blocks  = (int)((threads + 255) / 256);
        if (n_out % RPH == 0)
            gather_csr_kernel<false><<<blocks, 256, 0, stream>>>(
                feat1, feat2, offsets, idxpool, out, n_out);
        else
            gather_csr_kernel<true><<<blocks, 256, 0, stream>>>(
                feat1, feat2, offsets, idxpool, out, n_out);
    } else {
        long n4 = (long)out_size / 4;
        zero_out_kernel<<<2048, 256, 0, stream>>>((float4*)out, n4);
        scatter_add_kernel<<<(n1 + 3) / 4, 256, 0, stream>>>(
            feat1, map1_in, map1_out, out, n1, 0);
        scatter_add_kernel<<<(n2 + 3) / 4, 256, 0, stream>>>(
            feat2, map2_in, map2_out, out, n2, C_IN);
    }
}